// Round 13
// baseline (296.341 us; speedup 1.0000x reference)
//
#include <hip/hip_runtime.h>
#include <math.h>
#include <stdint.h>

// Problem constants
#define BB 4
#define TT 2048
#define NTOK 8192        // B*T
#define DIMD 512
#define HH 8
#define DHH 64
#define MLPD 2048
#define ADIMD 256
#define MODD 3072        // 6*DIM
#define LNEPS 1e-5f
#define LOG2E_8 0.18033688011112042f   // log2(e)/8
#define PBLK 2176        // partial block floats: 64*64 O as bf16 (=2048 f) + 128 (m,l)

typedef short short8 __attribute__((ext_vector_type(8)));
typedef unsigned short ushort4v __attribute__((ext_vector_type(4)));
typedef __bf16 bf16x8 __attribute__((ext_vector_type(8)));
typedef float f32x4 __attribute__((ext_vector_type(4)));

// f32 -> bf16 RNE via hardware cvt (v_cvt_pk_bf16_f32); pairs fuse to packed form
static __device__ __forceinline__ unsigned short f2bf(float f) {
    return __builtin_bit_cast(unsigned short, (__bf16)f);
}
static __device__ __forceinline__ float bf2f(unsigned short u) {
    union { unsigned u; float f; } v; v.u = (unsigned)u << 16; return v.f;
}
static __device__ __forceinline__ unsigned pk2bf(float a, float b) {
    return (unsigned)f2bf(a) | ((unsigned)f2bf(b) << 16);
}

static __device__ __forceinline__ f32x4 mfma_bf16(short8 a, short8 b, f32x4 c) {
    return __builtin_amdgcn_mfma_f32_16x16x32_bf16(
        __builtin_bit_cast(bf16x8, a), __builtin_bit_cast(bf16x8, b), c, 0, 0, 0);
}

// async global->LDS, 16 B per lane (global_load_lds_dwordx4)
static __device__ __forceinline__ void gload_lds16(const void* g, void* l) {
    __builtin_amdgcn_global_load_lds(
        (const __attribute__((address_space(1))) unsigned int*)g,
        (__attribute__((address_space(3))) unsigned int*)l, 16, 0, 0);
}

// ---------------------------------------------------------------------------
// Merged fp32->bf16 conversion: 5 weights + silu(action_emb), one launch
// ---------------------------------------------------------------------------
struct CvtArgs {
    const float* s[6];
    unsigned short* d[6];
    int cum[7];
};
__global__ __launch_bounds__(256) void cvt_all(CvtArgs a)
{
    const int i = blockIdx.x * 256 + threadIdx.x;
    if (i >= a.cum[6]) return;
    int seg = 0;
    #pragma unroll
    for (int k = 1; k < 6; k++) seg += (i >= a.cum[k]);
    const int off = i - a.cum[seg];
    float4 v = ((const float4*)a.s[seg])[off];
    if (seg == 5) {
        v.x = v.x / (1.f + __expf(-v.x));
        v.y = v.y / (1.f + __expf(-v.y));
        v.z = v.z / (1.f + __expf(-v.z));
        v.w = v.w / (1.f + __expf(-v.w));
    }
    uint2 o;
    o.x = pk2bf(v.x, v.y);
    o.y = pk2bf(v.z, v.w);
    ((uint2*)a.d[seg])[off] = o;
}

// ---------------------------------------------------------------------------
// bf16 MFMA NT GEMM v8 = v7 (r11 T1 XCD swizzle + r12 T2 source-swizzle,
// both WINs: FETCH 34->12.5MB, bank-conflicts 6.29M->~0, total -21us) with
// epilogue changes for the bf16-x_mid side-buffer:
// EPI: 0 bf16; 2 bf16 gelu(acc+bias); 3 BF16 x_mid = res + gate1*(acc+bias);
//      4 fp32 out = bf16_xmid(res) + gate2*(acc+bias); 5 bf16 acc+bias
// ---------------------------------------------------------------------------
template<int EPI, int BN>
__global__ __launch_bounds__(256, (BN == 128 ? 4 : 6)) void gemm_bf16(
    const unsigned short* __restrict__ A, const unsigned short* __restrict__ Bw,
    const float* __restrict__ bias, const float* __restrict__ res,
    const unsigned short* __restrict__ mod,
    int M, int N, int K,
    void* __restrict__ Cv)
{
    constexpr int MT = (BN == 128) ? 4 : 2;
    constexpr int NPB = BN / 32;
    __shared__ unsigned short As[128 * 64];
    __shared__ unsigned short Bs[BN * 64];

    const int tid = threadIdx.x;
    const int w = tid >> 6, lane = tid & 63;
    const int quad = lane >> 4, l16 = lane & 15;
    const int wrow = (BN == 128) ? (w >> 1) * 64 : w * 32;
    const int wcol = (BN == 128) ? (w & 1) * 64 : 0;

    // T1 XCD swizzle (r11 WIN): contiguous tile range per XCD -> panel L2 reuse.
    const int gx = gridDim.x;
    int lin = (int)(blockIdx.y * gx + blockIdx.x);
    const int per = (int)(gx * gridDim.y) >> 3;
    lin = (lin & 7) * per + (lin >> 3);
    const int row0 = (lin / gx) * 128, col0 = (lin % gx) * BN;

    const int srow = tid >> 3;                       // row within 32-row chunk
    const int skc  = (((tid & 7) ^ (srow & 7)) * 8); // T2: pre-swizzled source col (shorts)
    // LDS dest stays linear (tid*8 shorts); source chunk permuted per lane.

    f32x4 acc[MT][4];
    #pragma unroll
    for (int i = 0; i < MT; i++)
        #pragma unroll
        for (int j = 0; j < 4; j++) acc[i][j] = (f32x4){0.f, 0.f, 0.f, 0.f};

    auto stage_async = [&](int k0) {
        #pragma unroll
        for (int p = 0; p < 4; p++)
            gload_lds16(&A[(size_t)(row0 + srow + p * 32) * K + k0 + skc],
                        &As[p * 2048 + tid * 8]);
        #pragma unroll
        for (int p = 0; p < NPB; p++)
            gload_lds16(&Bw[(size_t)(col0 + srow + p * 32) * K + k0 + skc],
                        &Bs[p * 2048 + tid * 8]);
    };

    stage_async(0);
    __syncthreads();   // drains vmcnt(0): LDS tile ready

    const int xk = l16 & 7;                 // (row&7) for all fragment rows
    for (int k0 = 0; k0 < K; k0 += 64) {
        #pragma unroll
        for (int ks = 0; ks < 2; ks++) {
            const int cx = ((ks * 4 + quad) ^ xk) * 8;   // swizzled read chunk
            short8 af[MT], bf[4];
            #pragma unroll
            for (int mt = 0; mt < MT; mt++)
                af[mt] = *(const short8*)&As[(wrow + mt * 16 + l16) * 64 + cx];
            #pragma unroll
            for (int nt = 0; nt < 4; nt++)
                bf[nt] = *(const short8*)&Bs[(wcol + nt * 16 + l16) * 64 + cx];
            #pragma unroll
            for (int nt = 0; nt < 4; nt++)
                #pragma unroll
                for (int mt = 0; mt < MT; mt++)
                    acc[mt][nt] = mfma_bf16(af[mt], bf[nt], acc[mt][nt]);
        }
        __syncthreads();                       // all waves done reading LDS
        if (k0 + 64 < K) stage_async(k0 + 64); // async loads into same buffers
        __syncthreads();                       // vmcnt(0) drain: next tile ready
    }

    float* Cf = (float*)Cv;
    unsigned short* Cb = (unsigned short*)Cv;
    #pragma unroll
    for (int mt = 0; mt < MT; mt++) {
        #pragma unroll
        for (int r = 0; r < 4; r++) {
            const int row = row0 + wrow + mt * 16 + quad * 4 + r;
            #pragma unroll
            for (int nt = 0; nt < 4; nt++) {
                const int col = col0 + wcol + nt * 16 + l16;
                const size_t idx = (size_t)row * N + col;
                const float v = acc[mt][nt][r];
                if (EPI == 0) {
                    Cb[idx] = f2bf(v);
                } else if (EPI == 2) {
                    float t = v + bias[col];
                    Cb[idx] = f2bf(0.5f * t * (1.f + erff(t * 0.70710678118654752f)));
                } else if (EPI == 3) {
                    // bf16 x_mid = x + gate1*(acc+bias)  (res = x fp32)
                    float t = v + bias[col];
                    Cb[idx] = f2bf(res[idx] + bf2f(mod[(size_t)row * MODD + 1024 + col]) * t);
                } else if (EPI == 4) {
                    // fp32 out = bf16_xmid + gate2*(acc+bias)  (res = xmid bf16)
                    float t = v + bias[col];
                    const unsigned short* xm = (const unsigned short*)res;
                    Cf[idx] = bf2f(xm[idx]) + bf2f(mod[(size_t)row * MODD + 2560 + col]) * t;
                } else if (EPI == 5) {
                    Cb[idx] = f2bf(v + bias[col]);
                }
            }
        }
    }
}

// ---------------------------------------------------------------------------
// adaLN; BF16IN selects bf16 vs fp32 source (x_mid is now stored bf16)
// ---------------------------------------------------------------------------
template<int BF16IN>
__global__ __launch_bounds__(256) void adaln_ln(
    const void* __restrict__ src, const unsigned short* __restrict__ mod,
    unsigned short* __restrict__ dst, int shift_off, int scale_off)
{
    const int n = blockIdx.x;
    const int tid = threadIdx.x;
    float v0, v1;
    if (BF16IN) {
        const unsigned short* xr = (const unsigned short*)src + (size_t)n * DIMD;
        v0 = bf2f(xr[tid]); v1 = bf2f(xr[tid + 256]);
    } else {
        const float* xr = (const float*)src + (size_t)n * DIMD;
        v0 = xr[tid]; v1 = xr[tid + 256];
    }
    float s = v0 + v1;
    float q = v0 * v0 + v1 * v1;
    #pragma unroll
    for (int o = 32; o > 0; o >>= 1) {
        s += __shfl_down(s, o);
        q += __shfl_down(q, o);
    }
    __shared__ float sh[8];
    __shared__ float mu_sh, rs_sh;
    const int wid = tid >> 6, lane = tid & 63;
    if (lane == 0) { sh[wid] = s; sh[wid + 4] = q; }
    __syncthreads();
    if (tid == 0) {
        float S = sh[0] + sh[1] + sh[2] + sh[3];
        float Q = sh[4] + sh[5] + sh[6] + sh[7];
        float mu = S * (1.f / DIMD);
        float var = Q * (1.f / DIMD) - mu * mu;
        mu_sh = mu;
        rs_sh = rsqrtf(var + LNEPS);
    }
    __syncthreads();
    const float mu = mu_sh, rs = rs_sh;
    const unsigned short* mrow = mod + (size_t)n * MODD;
    const size_t o0 = (size_t)n * DIMD + tid;
    dst[o0]       = f2bf((v0 - mu) * rs * (1.f + bf2f(mrow[scale_off + tid]))       + bf2f(mrow[shift_off + tid]));
    dst[o0 + 256] = f2bf((v1 - mu) * rs * (1.f + bf2f(mrow[scale_off + tid + 256])) + bf2f(mrow[shift_off + tid + 256]));
}

// ---------------------------------------------------------------------------
// MFMA flash attention v11 = v10 (r10 WIN: Ps-LDS, hw cvt_pk, defer-max,
// bounds(256,5), bf16 O partials) + T5 s_setprio(1) around MFMA clusters.
// Mechanism (m191): 5 resident blocks/CU sit at DIFFERENT loop phases;
// boosting the MFMA-issuing wave's priority keeps the matrix pipe fed while
// other blocks' waves issue loads/VALU. (GEMMs stay without it: m190 null
// for barrier-lockstep structures.)
// ---------------------------------------------------------------------------
__global__ __launch_bounds__(256, 5) void attn_mfma(
    const unsigned short* __restrict__ qkv, float* __restrict__ part)
{
    __shared__ unsigned short Kt[64][76];     // K[kpos][d]
    __shared__ unsigned short Vt[64][76];     // V^T: Vt[d][kpos]
    __shared__ unsigned short Ps[4][16][76];  // per-wave P[q][kpos]

    const int f = 79 - (int)blockIdx.x;       // high-qi (4-chunk) blocks first
    int qi, ch;
    if (f < 8)       { qi = f;               ch = 0; }
    else if (f < 24) { const int g = f - 8;  qi = 8 + (g >> 1);  ch = g & 1; }
    else if (f < 48) { const int g = f - 24; qi = 16 + g / 3;    ch = g % 3; }
    else             { const int g = f - 48; qi = 24 + (g >> 2); ch = g & 3; }

    const int h = blockIdx.y, b = blockIdx.z;
    const int tid = threadIdx.x;
    const int w = tid >> 6;
    const int lane = tid & 63;
    const int quad = lane >> 4;
    const int l16 = lane & 15;

    const int qw = qi * 64 + w * 16;
    const size_t tokbase = (size_t)b * TT;

    // Q fragment (B operand of S^T = K·Q^T); log2(e)/8 folded in
    short8 qf[2];
    {
        const unsigned short* qp = qkv + (tokbase + qw + l16) * 1536 + h * 64 + quad * 8;
        #pragma unroll
        for (int hd = 0; hd < 2; hd++) {
            short8 raw = *(const short8*)(qp + hd * 32);
            short8 fr;
            #pragma unroll
            for (int j = 0; j < 8; j++)
                fr[j] = (short)f2bf(bf2f((unsigned short)raw[j]) * LOG2E_8);
            qf[hd] = fr;
        }
    }

    f32x4 Oa[4];   // col=l16=q, row=quad*4+r=d
    float mrun = -INFINITY, lrun = 0.f;
    #pragma unroll
    for (int mt = 0; mt < 4; mt++) Oa[mt] = (f32x4){0.f, 0.f, 0.f, 0.f};

    const int k0t = ch * 8;
    const int k1t = min(k0t + 8, qi + 1);
    const int vk0 = (tid & 31) * 2;
    const int vdb = (tid >> 5) * 8;

    short8 kpre[2], vpre[2];
    auto prefetchKV = [&](int kt) {
        const unsigned short* kb = qkv + (tokbase + (size_t)kt * 64) * 1536 + 512 + h * 64;
        #pragma unroll
        for (int it = 0; it < 2; it++) {
            const int i = tid + it * 256;
            kpre[it] = *(const short8*)(kb + (size_t)(i >> 3) * 1536 + (i & 7) * 8);
        }
        const unsigned short* vb = qkv + (tokbase + (size_t)kt * 64 + vk0) * 1536 + 1024 + h * 64 + vdb;
        vpre[0] = *(const short8*)vb;
        vpre[1] = *(const short8*)(vb + 1536);
    };
    auto storeKV = [&]() {
        #pragma unroll
        for (int it = 0; it < 2; it++) {
            const int i = tid + it * 256;
            *(short8*)&Kt[i >> 3][(i & 7) * 8] = kpre[it];
        }
        #pragma unroll
        for (int j = 0; j < 8; j++) {
            *(unsigned*)&Vt[vdb + j][vk0] =
                (unsigned)(unsigned short)vpre[0][j]
                | ((unsigned)(unsigned short)vpre[1][j] << 16);
        }
    };

    prefetchKV(k0t);
    storeKV();
    __syncthreads();

    for (int kt = k0t; kt < k1t; kt++) {
        const bool haveNext = (kt + 1 < k1t);
        if (haveNext) prefetchKV(kt + 1);

        // ---- S^T = K·Q^T ----
        f32x4 st[4];
        __builtin_amdgcn_s_setprio(1);
        #pragma unroll
        for (int mk = 0; mk < 4; mk++) {
            const short8 a0 = *(const short8*)&Kt[mk * 16 + l16][quad * 8];
            const short8 a1 = *(const short8*)&Kt[mk * 16 + l16][32 + quad * 8];
            st[mk] = (f32x4){0.f, 0.f, 0.f, 0.f};
            st[mk] = mfma_bf16(a0, qf[0], st[mk]);
            st[mk] = mfma_bf16(a1, qf[1], st[mk]);
        }
        __builtin_amdgcn_s_setprio(0);
        if (kt == qi) {   // diagonal tile
            const int qrel = w * 16 + l16;   // q within 64-row block
            #pragma unroll
            for (int mk = 0; mk < 4; mk++)
                #pragma unroll
                for (int r = 0; r < 4; r++)
                    if (mk * 16 + quad * 4 + r > qrel) st[mk][r] = -INFINITY;
        }
        // ---- per-lane softmax (defer-max) ----
        float tm = -INFINITY;
        #pragma unroll
        for (int mk = 0; mk < 4; mk++)
            #pragma unroll
            for (int r = 0; r < 4; r++) tm = fmaxf(tm, st[mk][r]);
        tm = fmaxf(tm, __shfl_xor(tm, 16));
        tm = fmaxf(tm, __shfl_xor(tm, 32));
        if (!__all(tm <= mrun + 8.0f)) {
            const float mn = fmaxf(mrun, tm);
            const float alpha = __builtin_amdgcn_exp2f(mrun - mn);
            lrun *= alpha;
            #pragma unroll
            for (int mt = 0; mt < 4; mt++) Oa[mt] *= alpha;
            mrun = mn;
        }
        float ts = 0.f;
        #pragma unroll
        for (int mk = 0; mk < 4; mk++) {
            const float p0 = __builtin_amdgcn_exp2f(st[mk][0] - mrun);
            const float p1 = __builtin_amdgcn_exp2f(st[mk][1] - mrun);
            const float p2 = __builtin_amdgcn_exp2f(st[mk][2] - mrun);
            const float p3 = __builtin_amdgcn_exp2f(st[mk][3] - mrun);
            ts += (p0 + p1) + (p2 + p3);
            const unsigned long long pk =
                (unsigned long long)pk2bf(p0, p1)
                | ((unsigned long long)pk2bf(p2, p3) << 32);
            *(unsigned long long*)&Ps[w][l16][mk * 16 + quad * 4] = pk;
        }
        ts += __shfl_xor(ts, 16);
        ts += __shfl_xor(ts, 32);
        lrun += ts;
        __threadfence_block();

        // ---- O^T += V^T·P^T ----
        short8 pf[2];
        #pragma unroll
        for (int kc = 0; kc < 2; kc++)
            pf[kc] = *(const short8*)&Ps[w][l16][kc * 32 + quad * 8];
        __builtin_amdgcn_s_setprio(1);
        #pragma unroll
        for (int mt = 0; mt < 4; mt++)
            #pragma unroll
            for (int kc = 0; kc < 2; kc++) {
                const short8 vf = *(const short8*)&Vt[mt * 16 + l16][kc * 32 + quad * 8];
                Oa[mt] = mfma_bf16(vf, pf[kc], Oa[mt]);
            }
        __builtin_amdgcn_s_setprio(0);

        __syncthreads();
        if (haveNext) storeKV();
        __syncthreads();
    }

    // ---- write partial: O [q][d] bf16 (2048 f-slots), then (m,l) fp32 ----
    float* pO = part + ((size_t)((b * HH + h) * 80 + f)) * PBLK;
    unsigned short* pOb = (unsigned short*)pO;
    #pragma unroll
    for (int mt = 0; mt < 4; mt++) {
        uint2 o;
        o.x = pk2bf(Oa[mt][0], Oa[mt][1]);
        o.y = pk2bf(Oa[mt][2], Oa[mt][3]);
        *(uint2*)&pOb[(w * 16 + l16) * 64 + mt * 16 + quad * 4] = o;
    }
    if (quad == 0) {
        pO[2048 + (w * 16 + l16) * 2]     = mrun;
        pO[2048 + (w * 16 + l16) * 2 + 1] = lrun;
    }
}

// ---------------------------------------------------------------------------
// Combine split-K partials: out = (sum_c e^{m_c-M} O_c) / (sum_c e^{m_c-M} l_c)
// O partial is bf16; m,l fp32. Thread = (tok, h, 4-d group).
// ---------------------------------------------------------------------------
__global__ __launch_bounds__(256) void attn_combine(
    const float* __restrict__ part, unsigned short* __restrict__ outb)
{
    const int idx = blockIdx.x * 256 + threadIdx.x;
    const int d4 = idx & 15;
    const int h = (idx >> 4) & 7;
    const int tok = idx >> 7;
    const int t = tok & (TT - 1);
    const int b = tok >> 11;
    const int qi = t >> 6;
    const int nch = (qi >> 3) + 1;
    int cum;
    if (qi < 8)       cum = qi;
    else if (qi < 16) cum = 8 + ((qi - 8) << 1);
    else if (qi < 24) cum = 24 + (qi - 16) * 3;
    else              cum = 48 + ((qi - 24) << 2);
    const int qloc = t & 63;
    const float* base = part + ((size_t)((b * HH + h) * 80 + cum)) * PBLK;

    float M = -INFINITY;
    for (int c = 0; c < nch; c++)
        M = fmaxf(M, base[c * PBLK + 2048 + qloc * 2]);
    float L = 0.f, a0 = 0.f, a1 = 0.f, a2 = 0.f, a3 = 0.f;
    for (int c = 0; c < nch; c++) {
        const float* pc = base + (size_t)c * PBLK;
        const float m = pc[2048 + qloc * 2];
        const float l = pc[2048 + qloc * 2 + 1];
        const float sc = __builtin_amdgcn_exp2f(m - M);
        L += l * sc;
        const uint2 o = *(const uint2*)&((const unsigned short*)pc)[qloc * 64 + d4 * 4];
        a0 += sc * bf2f((unsigned short)(o.x & 0xffffu));
        a1 += sc * bf2f((unsigned short)(o.x >> 16));
        a2 += sc * bf2f((unsigned short)(o.y & 0xffffu));
        a3 += sc * bf2f((unsigned short)(o.y >> 16));
    }
    const float inv = 1.f / L;
    const unsigned long long pk =
        (unsigned long long)pk2bf(a0 * inv, a1 * inv)
        | ((unsigned long long)pk2bf(a2 * inv, a3 * inv) << 32);
    *(unsigned long long*)&outb[(size_t)tok * DIMD + h * 64 + d4 * 4] = pk;
}

// ---------------------------------------------------------------------------
extern "C" void kernel_launch(void* const* d_in, const int* in_sizes, int n_in,
                              void* d_out, int out_size, void* d_ws, size_t ws_size,
                              hipStream_t stream)
{
    (void)in_sizes; (void)n_in; (void)out_size; (void)ws_size;

    const float* x    = (const float*)d_in[0];
    const float* aemb = (const float*)d_in[1];
    const float* Wqkv = (const float*)d_in[3];
    const float* Wout = (const float*)d_in[4];
    const float* bout = (const float*)d_in[5];
    const float* W1   = (const float*)d_in[6];
    const float* b1   = (const float*)d_in[7];
    const float* W2   = (const float*)d_in[8];
    const float* b2   = (const float*)d_in[9];
    const float* Wmod = (const float*)d_in[10];
    const float* bmod = (const float*)d_in[11];

    float* out = (float*)d_out;

    // workspace layout
    char* p = (char*)d_ws;
    unsigned short* modw = (unsigned short*)p; p += (size_t)NTOK * MODD * 2;
    unsigned short* h12  = (unsigned short*)p; p += (size_t)NTOK * DIMD * 2;
    unsigned short* qkvb = (unsigned short*)p; p += (size_t)NTOK * 1536 * 2;
    unsigned short* attw = (unsigned short*)p; p += (size_t)NTOK * DIMD * 2;
    unsigned short* hid  = qkvb;        // reuses qkvb+attw
    unsigned short* xmid = (unsigned short*)p; p += (size_t)NTOK * DIMD * 2;  // bf16 x_mid
    unsigned short* sact = (unsigned short*)p; p += (size_t)NTOK * ADIMD * 2;
    unsigned short* wq = (unsigned short*)p;   p += (size_t)1536 * 512 * 2;
    unsigned short* wo = (unsigned short*)p;   p += (size_t)512 * 512 * 2;
    unsigned short* w1 = (unsigned short*)p;   p += (size_t)2048 * 512 * 2;
    unsigned short* w2 = (unsigned short*)p;   p += (size_t)512 * 2048 * 2;
    unsigned short* wm = (unsigned short*)p;   p += (size_t)3072 * 256 * 2;
    p = (char*)(((uintptr_t)p + 255) & ~(uintptr_t)255);
    float* part = (float*)p;                   // 32*80*PBLK*4 = 22.3 MB

    // 0) all dtype conversions in one launch
    CvtArgs ca;
    ca.s[0] = Wqkv; ca.d[0] = wq;
    ca.s[1] = Wout; ca.d[1] = wo;
    ca.s[2] = W1;   ca.d[2] = w1;
    ca.s[3] = W2;   ca.d[3] = w2;
    ca.s[4] = Wmod; ca.d[4] = wm;
    ca.s[5] = aemb; ca.d[5] = sact;
    const int n4s[6] = {1536 * 512 / 4, 512 * 512 / 4, 2048 * 512 / 4,
                        512 * 2048 / 4, 3072 * 256 / 4, NTOK * ADIMD / 4};
    ca.cum[0] = 0;
    for (int i = 0; i < 6; i++) ca.cum[i + 1] = ca.cum[i] + n4s[i];
    cvt_all<<<(ca.cum[6] + 255) / 256, 256, 0, stream>>>(ca);

    // 1) mod = silu(action_emb) @ Wmod^T + bmod  (bf16 out)
    gemm_bf16<5, 128><<<dim3(MODD / 128, NTOK / 128), 256, 0, stream>>>(
        sact, wm, bmod, nullptr, nullptr, NTOK, MODD, ADIMD, modw);

    // 2) h1 = LN(x)*(1+scale1)+shift1  (bf16 out; x fp32)
    adaln_ln<0><<<NTOK, 256, 0, stream>>>(x, modw, h12, 0, 512);

    // 3) qkv = h1 @ Wqkv^T  (bf16 out)
    gemm_bf16<0, 128><<<dim3(1536 / 128, NTOK / 128), 256, 0, stream>>>(
        h12, wq, nullptr, nullptr, nullptr, NTOK, 1536, DIMD, qkvb);

    // 4) attention: split-K partials + combine
    attn_mfma<<<dim3(80, HH, BB), 256, 0, stream>>>(qkvb, part);
    attn_combine<<<NTOK * HH * 16 / 256, 256, 0, stream>>>(part, attw);

    // 5) x_mid = x + gate1 * (attw @ Wout^T + bout)  (bf16 out -> xmid)
    gemm_bf16<3, 64><<<dim3(DIMD / 64, NTOK / 128), 256, 0, stream>>>(
        attw, wo, bout, x, modw, NTOK, DIMD, DIMD, xmid);

    // 6) h2 = LN(x_mid)*(1+scale2)+shift2  (bf16 out; x_mid bf16)
    adaln_ln<1><<<NTOK, 256, 0, stream>>>(xmid, modw, h12, 1536, 2048);

    // 7) hid = gelu(h2 @ W1^T + b1)  (bf16 out)
    gemm_bf16<2, 128><<<dim3(MLPD / 128, NTOK / 128), 256, 0, stream>>>(
        h12, w1, b1, nullptr, nullptr, NTOK, MLPD, DIMD, hid);

    // 8) d_out = x_mid + gate2 * (hid @ W2^T + b2)  (fp32 out; xmid bf16 read)
    gemm_bf16<4, 64><<<dim3(DIMD / 64, NTOK / 128), 256, 0, stream>>>(
        hid, w2, b2, (const float*)xmid, modw, NTOK, DIMD, MLPD, out);
}

// Round 14
// 285.759 us; speedup vs baseline: 1.0370x; 1.0370x over previous
//
#include <hip/hip_runtime.h>
#include <math.h>
#include <stdint.h>

// Problem constants
#define BB 4
#define TT 2048
#define NTOK 8192        // B*T
#define DIMD 512
#define HH 8
#define DHH 64
#define MLPD 2048
#define ADIMD 256
#define MODD 3072        // 6*DIM
#define LNEPS 1e-5f
#define LOG2E_8 0.18033688011112042f   // log2(e)/8
#define PBLK 2176        // partial block floats: 64*64 O as bf16 (=2048 f) + 128 (m,l)

typedef short short8 __attribute__((ext_vector_type(8)));
typedef unsigned short ushort4v __attribute__((ext_vector_type(4)));
typedef __bf16 bf16x8 __attribute__((ext_vector_type(8)));
typedef float f32x4 __attribute__((ext_vector_type(4)));

// f32 -> bf16 RNE via hardware cvt (v_cvt_pk_bf16_f32); pairs fuse to packed form
static __device__ __forceinline__ unsigned short f2bf(float f) {
    return __builtin_bit_cast(unsigned short, (__bf16)f);
}
static __device__ __forceinline__ float bf2f(unsigned short u) {
    union { unsigned u; float f; } v; v.u = (unsigned)u << 16; return v.f;
}
static __device__ __forceinline__ unsigned pk2bf(float a, float b) {
    return (unsigned)f2bf(a) | ((unsigned)f2bf(b) << 16);
}

static __device__ __forceinline__ f32x4 mfma_bf16(short8 a, short8 b, f32x4 c) {
    return __builtin_amdgcn_mfma_f32_16x16x32_bf16(
        __builtin_bit_cast(bf16x8, a), __builtin_bit_cast(bf16x8, b), c, 0, 0, 0);
}

// async global->LDS, 16 B per lane (global_load_lds_dwordx4)
static __device__ __forceinline__ void gload_lds16(const void* g, void* l) {
    __builtin_amdgcn_global_load_lds(
        (const __attribute__((address_space(1))) unsigned int*)g,
        (__attribute__((address_space(3))) unsigned int*)l, 16, 0, 0);
}

// ---------------------------------------------------------------------------
// Merged fp32->bf16 conversion: 5 weights + silu(action_emb), one launch
// ---------------------------------------------------------------------------
struct CvtArgs {
    const float* s[6];
    unsigned short* d[6];
    int cum[7];
};
__global__ __launch_bounds__(256) void cvt_all(CvtArgs a)
{
    const int i = blockIdx.x * 256 + threadIdx.x;
    if (i >= a.cum[6]) return;
    int seg = 0;
    #pragma unroll
    for (int k = 1; k < 6; k++) seg += (i >= a.cum[k]);
    const int off = i - a.cum[seg];
    float4 v = ((const float4*)a.s[seg])[off];
    if (seg == 5) {
        v.x = v.x / (1.f + __expf(-v.x));
        v.y = v.y / (1.f + __expf(-v.y));
        v.z = v.z / (1.f + __expf(-v.z));
        v.w = v.w / (1.f + __expf(-v.w));
    }
    uint2 o;
    o.x = pk2bf(v.x, v.y);
    o.y = pk2bf(v.z, v.w);
    ((uint2*)a.d[seg])[off] = o;
}

// ---------------------------------------------------------------------------
// bf16 MFMA NT GEMM v8 (r11 T1 XCD swizzle + r12 T2 source-swizzle, both
// WINs) with bf16-x_mid epilogues (r13; de-bundled from setprio in r14):
// EPI: 0 bf16; 2 bf16 gelu(acc+bias); 3 BF16 x_mid = res + gate1*(acc+bias);
//      4 fp32 out = bf16_xmid(res) + gate2*(acc+bias); 5 bf16 acc+bias
// ---------------------------------------------------------------------------
template<int EPI, int BN>
__global__ __launch_bounds__(256, (BN == 128 ? 4 : 6)) void gemm_bf16(
    const unsigned short* __restrict__ A, const unsigned short* __restrict__ Bw,
    const float* __restrict__ bias, const float* __restrict__ res,
    const unsigned short* __restrict__ mod,
    int M, int N, int K,
    void* __restrict__ Cv)
{
    constexpr int MT = (BN == 128) ? 4 : 2;
    constexpr int NPB = BN / 32;
    __shared__ unsigned short As[128 * 64];
    __shared__ unsigned short Bs[BN * 64];

    const int tid = threadIdx.x;
    const int w = tid >> 6, lane = tid & 63;
    const int quad = lane >> 4, l16 = lane & 15;
    const int wrow = (BN == 128) ? (w >> 1) * 64 : w * 32;
    const int wcol = (BN == 128) ? (w & 1) * 64 : 0;

    // T1 XCD swizzle (r11 WIN): contiguous tile range per XCD -> panel L2 reuse.
    const int gx = gridDim.x;
    int lin = (int)(blockIdx.y * gx + blockIdx.x);
    const int per = (int)(gx * gridDim.y) >> 3;
    lin = (lin & 7) * per + (lin >> 3);
    const int row0 = (lin / gx) * 128, col0 = (lin % gx) * BN;

    const int srow = tid >> 3;                       // row within 32-row chunk
    const int skc  = (((tid & 7) ^ (srow & 7)) * 8); // T2: pre-swizzled source col (shorts)
    // LDS dest stays linear (tid*8 shorts); source chunk permuted per lane.

    f32x4 acc[MT][4];
    #pragma unroll
    for (int i = 0; i < MT; i++)
        #pragma unroll
        for (int j = 0; j < 4; j++) acc[i][j] = (f32x4){0.f, 0.f, 0.f, 0.f};

    auto stage_async = [&](int k0) {
        #pragma unroll
        for (int p = 0; p < 4; p++)
            gload_lds16(&A[(size_t)(row0 + srow + p * 32) * K + k0 + skc],
                        &As[p * 2048 + tid * 8]);
        #pragma unroll
        for (int p = 0; p < NPB; p++)
            gload_lds16(&Bw[(size_t)(col0 + srow + p * 32) * K + k0 + skc],
                        &Bs[p * 2048 + tid * 8]);
    };

    stage_async(0);
    __syncthreads();   // drains vmcnt(0): LDS tile ready

    const int xk = l16 & 7;                 // (row&7) for all fragment rows
    for (int k0 = 0; k0 < K; k0 += 64) {
        #pragma unroll
        for (int ks = 0; ks < 2; ks++) {
            const int cx = ((ks * 4 + quad) ^ xk) * 8;   // swizzled read chunk
            short8 af[MT], bf[4];
            #pragma unroll
            for (int mt = 0; mt < MT; mt++)
                af[mt] = *(const short8*)&As[(wrow + mt * 16 + l16) * 64 + cx];
            #pragma unroll
            for (int nt = 0; nt < 4; nt++)
                bf[nt] = *(const short8*)&Bs[(wcol + nt * 16 + l16) * 64 + cx];
            #pragma unroll
            for (int nt = 0; nt < 4; nt++)
                #pragma unroll
                for (int mt = 0; mt < MT; mt++)
                    acc[mt][nt] = mfma_bf16(af[mt], bf[nt], acc[mt][nt]);
        }
        __syncthreads();                       // all waves done reading LDS
        if (k0 + 64 < K) stage_async(k0 + 64); // async loads into same buffers
        __syncthreads();                       // vmcnt(0) drain: next tile ready
    }

    float* Cf = (float*)Cv;
    unsigned short* Cb = (unsigned short*)Cv;
    #pragma unroll
    for (int mt = 0; mt < MT; mt++) {
        #pragma unroll
        for (int r = 0; r < 4; r++) {
            const int row = row0 + wrow + mt * 16 + quad * 4 + r;
            #pragma unroll
            for (int nt = 0; nt < 4; nt++) {
                const int col = col0 + wcol + nt * 16 + l16;
                const size_t idx = (size_t)row * N + col;
                const float v = acc[mt][nt][r];
                if (EPI == 0) {
                    Cb[idx] = f2bf(v);
                } else if (EPI == 2) {
                    float t = v + bias[col];
                    Cb[idx] = f2bf(0.5f * t * (1.f + erff(t * 0.70710678118654752f)));
                } else if (EPI == 3) {
                    // bf16 x_mid = x + gate1*(acc+bias)  (res = x fp32)
                    float t = v + bias[col];
                    Cb[idx] = f2bf(res[idx] + bf2f(mod[(size_t)row * MODD + 1024 + col]) * t);
                } else if (EPI == 4) {
                    // fp32 out = bf16_xmid + gate2*(acc+bias)  (res = xmid bf16)
                    float t = v + bias[col];
                    const unsigned short* xm = (const unsigned short*)res;
                    Cf[idx] = bf2f(xm[idx]) + bf2f(mod[(size_t)row * MODD + 2560 + col]) * t;
                } else if (EPI == 5) {
                    Cb[idx] = f2bf(v + bias[col]);
                }
            }
        }
    }
}

// ---------------------------------------------------------------------------
// adaLN; BF16IN selects bf16 vs fp32 source (x_mid is stored bf16)
// ---------------------------------------------------------------------------
template<int BF16IN>
__global__ __launch_bounds__(256) void adaln_ln(
    const void* __restrict__ src, const unsigned short* __restrict__ mod,
    unsigned short* __restrict__ dst, int shift_off, int scale_off)
{
    const int n = blockIdx.x;
    const int tid = threadIdx.x;
    float v0, v1;
    if (BF16IN) {
        const unsigned short* xr = (const unsigned short*)src + (size_t)n * DIMD;
        v0 = bf2f(xr[tid]); v1 = bf2f(xr[tid + 256]);
    } else {
        const float* xr = (const float*)src + (size_t)n * DIMD;
        v0 = xr[tid]; v1 = xr[tid + 256];
    }
    float s = v0 + v1;
    float q = v0 * v0 + v1 * v1;
    #pragma unroll
    for (int o = 32; o > 0; o >>= 1) {
        s += __shfl_down(s, o);
        q += __shfl_down(q, o);
    }
    __shared__ float sh[8];
    __shared__ float mu_sh, rs_sh;
    const int wid = tid >> 6, lane = tid & 63;
    if (lane == 0) { sh[wid] = s; sh[wid + 4] = q; }
    __syncthreads();
    if (tid == 0) {
        float S = sh[0] + sh[1] + sh[2] + sh[3];
        float Q = sh[4] + sh[5] + sh[6] + sh[7];
        float mu = S * (1.f / DIMD);
        float var = Q * (1.f / DIMD) - mu * mu;
        mu_sh = mu;
        rs_sh = rsqrtf(var + LNEPS);
    }
    __syncthreads();
    const float mu = mu_sh, rs = rs_sh;
    const unsigned short* mrow = mod + (size_t)n * MODD;
    const size_t o0 = (size_t)n * DIMD + tid;
    dst[o0]       = f2bf((v0 - mu) * rs * (1.f + bf2f(mrow[scale_off + tid]))       + bf2f(mrow[shift_off + tid]));
    dst[o0 + 256] = f2bf((v1 - mu) * rs * (1.f + bf2f(mrow[scale_off + tid + 256])) + bf2f(mrow[shift_off + tid + 256]));
}

// ---------------------------------------------------------------------------
// MFMA flash attention v10 (r10/r12 WIN version, setprio REMOVED in r14 to
// de-bundle the r13 experiment): Ps-LDS inner loop, hw cvt_pk, defer-max,
// bounds(256,5), bf16 O partials (m,l fp32).
// ---------------------------------------------------------------------------
__global__ __launch_bounds__(256, 5) void attn_mfma(
    const unsigned short* __restrict__ qkv, float* __restrict__ part)
{
    __shared__ unsigned short Kt[64][76];     // K[kpos][d]
    __shared__ unsigned short Vt[64][76];     // V^T: Vt[d][kpos]
    __shared__ unsigned short Ps[4][16][76];  // per-wave P[q][kpos]

    const int f = 79 - (int)blockIdx.x;       // high-qi (4-chunk) blocks first
    int qi, ch;
    if (f < 8)       { qi = f;               ch = 0; }
    else if (f < 24) { const int g = f - 8;  qi = 8 + (g >> 1);  ch = g & 1; }
    else if (f < 48) { const int g = f - 24; qi = 16 + g / 3;    ch = g % 3; }
    else             { const int g = f - 48; qi = 24 + (g >> 2); ch = g & 3; }

    const int h = blockIdx.y, b = blockIdx.z;
    const int tid = threadIdx.x;
    const int w = tid >> 6;
    const int lane = tid & 63;
    const int quad = lane >> 4;
    const int l16 = lane & 15;

    const int qw = qi * 64 + w * 16;
    const size_t tokbase = (size_t)b * TT;

    // Q fragment (B operand of S^T = K·Q^T); log2(e)/8 folded in
    short8 qf[2];
    {
        const unsigned short* qp = qkv + (tokbase + qw + l16) * 1536 + h * 64 + quad * 8;
        #pragma unroll
        for (int hd = 0; hd < 2; hd++) {
            short8 raw = *(const short8*)(qp + hd * 32);
            short8 fr;
            #pragma unroll
            for (int j = 0; j < 8; j++)
                fr[j] = (short)f2bf(bf2f((unsigned short)raw[j]) * LOG2E_8);
            qf[hd] = fr;
        }
    }

    f32x4 Oa[4];   // col=l16=q, row=quad*4+r=d
    float mrun = -INFINITY, lrun = 0.f;
    #pragma unroll
    for (int mt = 0; mt < 4; mt++) Oa[mt] = (f32x4){0.f, 0.f, 0.f, 0.f};

    const int k0t = ch * 8;
    const int k1t = min(k0t + 8, qi + 1);
    const int vk0 = (tid & 31) * 2;
    const int vdb = (tid >> 5) * 8;

    short8 kpre[2], vpre[2];
    auto prefetchKV = [&](int kt) {
        const unsigned short* kb = qkv + (tokbase + (size_t)kt * 64) * 1536 + 512 + h * 64;
        #pragma unroll
        for (int it = 0; it < 2; it++) {
            const int i = tid + it * 256;
            kpre[it] = *(const short8*)(kb + (size_t)(i >> 3) * 1536 + (i & 7) * 8);
        }
        const unsigned short* vb = qkv + (tokbase + (size_t)kt * 64 + vk0) * 1536 + 1024 + h * 64 + vdb;
        vpre[0] = *(const short8*)vb;
        vpre[1] = *(const short8*)(vb + 1536);
    };
    auto storeKV = [&]() {
        #pragma unroll
        for (int it = 0; it < 2; it++) {
            const int i = tid + it * 256;
            *(short8*)&Kt[i >> 3][(i & 7) * 8] = kpre[it];
        }
        #pragma unroll
        for (int j = 0; j < 8; j++) {
            *(unsigned*)&Vt[vdb + j][vk0] =
                (unsigned)(unsigned short)vpre[0][j]
                | ((unsigned)(unsigned short)vpre[1][j] << 16);
        }
    };

    prefetchKV(k0t);
    storeKV();
    __syncthreads();

    for (int kt = k0t; kt < k1t; kt++) {
        const bool haveNext = (kt + 1 < k1t);
        if (haveNext) prefetchKV(kt + 1);

        // ---- S^T = K·Q^T ----
        f32x4 st[4];
        #pragma unroll
        for (int mk = 0; mk < 4; mk++) {
            const short8 a0 = *(const short8*)&Kt[mk * 16 + l16][quad * 8];
            const short8 a1 = *(const short8*)&Kt[mk * 16 + l16][32 + quad * 8];
            st[mk] = (f32x4){0.f, 0.f, 0.f, 0.f};
            st[mk] = mfma_bf16(a0, qf[0], st[mk]);
            st[mk] = mfma_bf16(a1, qf[1], st[mk]);
        }
        if (kt == qi) {   // diagonal tile
            const int qrel = w * 16 + l16;   // q within 64-row block
            #pragma unroll
            for (int mk = 0; mk < 4; mk++)
                #pragma unroll
                for (int r = 0; r < 4; r++)
                    if (mk * 16 + quad * 4 + r > qrel) st[mk][r] = -INFINITY;
        }
        // ---- per-lane softmax (defer-max) ----
        float tm = -INFINITY;
        #pragma unroll
        for (int mk = 0; mk < 4; mk++)
            #pragma unroll
            for (int r = 0; r < 4; r++) tm = fmaxf(tm, st[mk][r]);
        tm = fmaxf(tm, __shfl_xor(tm, 16));
        tm = fmaxf(tm, __shfl_xor(tm, 32));
        if (!__all(tm <= mrun + 8.0f)) {
            const float mn = fmaxf(mrun, tm);
            const float alpha = __builtin_amdgcn_exp2f(mrun - mn);
            lrun *= alpha;
            #pragma unroll
            for (int mt = 0; mt < 4; mt++) Oa[mt] *= alpha;
            mrun = mn;
        }
        float ts = 0.f;
        #pragma unroll
        for (int mk = 0; mk < 4; mk++) {
            const float p0 = __builtin_amdgcn_exp2f(st[mk][0] - mrun);
            const float p1 = __builtin_amdgcn_exp2f(st[mk][1] - mrun);
            const float p2 = __builtin_amdgcn_exp2f(st[mk][2] - mrun);
            const float p3 = __builtin_amdgcn_exp2f(st[mk][3] - mrun);
            ts += (p0 + p1) + (p2 + p3);
            const unsigned long long pk =
                (unsigned long long)pk2bf(p0, p1)
                | ((unsigned long long)pk2bf(p2, p3) << 32);
            *(unsigned long long*)&Ps[w][l16][mk * 16 + quad * 4] = pk;
        }
        ts += __shfl_xor(ts, 16);
        ts += __shfl_xor(ts, 32);
        lrun += ts;
        __threadfence_block();

        // ---- O^T += V^T·P^T ----
        short8 pf[2];
        #pragma unroll
        for (int kc = 0; kc < 2; kc++)
            pf[kc] = *(const short8*)&Ps[w][l16][kc * 32 + quad * 8];
        #pragma unroll
        for (int mt = 0; mt < 4; mt++)
            #pragma unroll
            for (int kc = 0; kc < 2; kc++) {
                const short8 vf = *(const short8*)&Vt[mt * 16 + l16][kc * 32 + quad * 8];
                Oa[mt] = mfma_bf16(vf, pf[kc], Oa[mt]);
            }

        __syncthreads();
        if (haveNext) storeKV();
        __syncthreads();
    }

    // ---- write partial: O [q][d] bf16 (2048 f-slots), then (m,l) fp32 ----
    float* pO = part + ((size_t)((b * HH + h) * 80 + f)) * PBLK;
    unsigned short* pOb = (unsigned short*)pO;
    #pragma unroll
    for (int mt = 0; mt < 4; mt++) {
        uint2 o;
        o.x = pk2bf(Oa[mt][0], Oa[mt][1]);
        o.y = pk2bf(Oa[mt][2], Oa[mt][3]);
        *(uint2*)&pOb[(w * 16 + l16) * 64 + mt * 16 + quad * 4] = o;
    }
    if (quad == 0) {
        pO[2048 + (w * 16 + l16) * 2]     = mrun;
        pO[2048 + (w * 16 + l16) * 2 + 1] = lrun;
    }
}

// ---------------------------------------------------------------------------
// Combine split-K partials: out = (sum_c e^{m_c-M} O_c) / (sum_c e^{m_c-M} l_c)
// O partial is bf16; m,l fp32. Thread = (tok, h, 4-d group).
// ---------------------------------------------------------------------------
__global__ __launch_bounds__(256) void attn_combine(
    const float* __restrict__ part, unsigned short* __restrict__ outb)
{
    const int idx = blockIdx.x * 256 + threadIdx.x;
    const int d4 = idx & 15;
    const int h = (idx >> 4) & 7;
    const int tok = idx >> 7;
    const int t = tok & (TT - 1);
    const int b = tok >> 11;
    const int qi = t >> 6;
    const int nch = (qi >> 3) + 1;
    int cum;
    if (qi < 8)       cum = qi;
    else if (qi < 16) cum = 8 + ((qi - 8) << 1);
    else if (qi < 24) cum = 24 + (qi - 16) * 3;
    else              cum = 48 + ((qi - 24) << 2);
    const int qloc = t & 63;
    const float* base = part + ((size_t)((b * HH + h) * 80 + cum)) * PBLK;

    float M = -INFINITY;
    for (int c = 0; c < nch; c++)
        M = fmaxf(M, base[c * PBLK + 2048 + qloc * 2]);
    float L = 0.f, a0 = 0.f, a1 = 0.f, a2 = 0.f, a3 = 0.f;
    for (int c = 0; c < nch; c++) {
        const float* pc = base + (size_t)c * PBLK;
        const float m = pc[2048 + qloc * 2];
        const float l = pc[2048 + qloc * 2 + 1];
        const float sc = __builtin_amdgcn_exp2f(m - M);
        L += l * sc;
        const uint2 o = *(const uint2*)&((const unsigned short*)pc)[qloc * 64 + d4 * 4];
        a0 += sc * bf2f((unsigned short)(o.x & 0xffffu));
        a1 += sc * bf2f((unsigned short)(o.x >> 16));
        a2 += sc * bf2f((unsigned short)(o.y & 0xffffu));
        a3 += sc * bf2f((unsigned short)(o.y >> 16));
    }
    const float inv = 1.f / L;
    const unsigned long long pk =
        (unsigned long long)pk2bf(a0 * inv, a1 * inv)
        | ((unsigned long long)pk2bf(a2 * inv, a3 * inv) << 32);
    *(unsigned long long*)&outb[(size_t)tok * DIMD + h * 64 + d4 * 4] = pk;
}

// ---------------------------------------------------------------------------
extern "C" void kernel_launch(void* const* d_in, const int* in_sizes, int n_in,
                              void* d_out, int out_size, void* d_ws, size_t ws_size,
                              hipStream_t stream)
{
    (void)in_sizes; (void)n_in; (void)out_size; (void)ws_size;

    const float* x    = (const float*)d_in[0];
    const float* aemb = (const float*)d_in[1];
    const float* Wqkv = (const float*)d_in[3];
    const float* Wout = (const float*)d_in[4];
    const float* bout = (const float*)d_in[5];
    const float* W1   = (const float*)d_in[6];
    const float* b1   = (const float*)d_in[7];
    const float* W2   = (const float*)d_in[8];
    const float* b2   = (const float*)d_in[9];
    const float* Wmod = (const float*)d_in[10];
    const float* bmod = (const float*)d_in[11];

    float* out = (float*)d_out;

    // workspace layout
    char* p = (char*)d_ws;
    unsigned short* modw = (unsigned short*)p; p += (size_t)NTOK * MODD * 2;
    unsigned short* h12  = (unsigned short*)p; p += (size_t)NTOK * DIMD * 2;
    unsigned short* qkvb = (unsigned short*)p; p += (size_t)NTOK * 1536 * 2;
    unsigned short* attw = (unsigned short*)p; p += (size_t)NTOK * DIMD * 2;
    unsigned short* hid  = qkvb;        // reuses qkvb+attw
    unsigned short* xmid = (unsigned short*)p; p += (size_t)NTOK * DIMD * 2;  // bf16 x_mid
    unsigned short* sact = (unsigned short*)p; p += (size_t)NTOK * ADIMD * 2;
    unsigned short* wq = (unsigned short*)p;   p += (size_t)1536 * 512 * 2;
    unsigned short* wo = (unsigned short*)p;   p += (size_t)512 * 512 * 2;
    unsigned short* w1 = (unsigned short*)p;   p += (size_t)2048 * 512 * 2;
    unsigned short* w2 = (unsigned short*)p;   p += (size_t)512 * 2048 * 2;
    unsigned short* wm = (unsigned short*)p;   p += (size_t)3072 * 256 * 2;
    p = (char*)(((uintptr_t)p + 255) & ~(uintptr_t)255);
    float* part = (float*)p;                   // 32*80*PBLK*4 = 22.3 MB

    // 0) all dtype conversions in one launch
    CvtArgs ca;
    ca.s[0] = Wqkv; ca.d[0] = wq;
    ca.s[1] = Wout; ca.d[1] = wo;
    ca.s[2] = W1;   ca.d[2] = w1;
    ca.s[3] = W2;   ca.d[3] = w2;
    ca.s[4] = Wmod; ca.d[4] = wm;
    ca.s[5] = aemb; ca.d[5] = sact;
    const int n4s[6] = {1536 * 512 / 4, 512 * 512 / 4, 2048 * 512 / 4,
                        512 * 2048 / 4, 3072 * 256 / 4, NTOK * ADIMD / 4};
    ca.cum[0] = 0;
    for (int i = 0; i < 6; i++) ca.cum[i + 1] = ca.cum[i] + n4s[i];
    cvt_all<<<(ca.cum[6] + 255) / 256, 256, 0, stream>>>(ca);

    // 1) mod = silu(action_emb) @ Wmod^T + bmod  (bf16 out)
    gemm_bf16<5, 128><<<dim3(MODD / 128, NTOK / 128), 256, 0, stream>>>(
        sact, wm, bmod, nullptr, nullptr, NTOK, MODD, ADIMD, modw);

    // 2) h1 = LN(x)*(1+scale1)+shift1  (bf16 out; x fp32)
    adaln_ln<0><<<NTOK, 256, 0, stream>>>(x, modw, h12, 0, 512);

    // 3) qkv = h1 @ Wqkv^T  (bf16 out)
    gemm_bf16<0, 128><<<dim3(1536 / 128, NTOK / 128), 256, 0, stream>>>(
        h12, wq, nullptr, nullptr, nullptr, NTOK, 1536, DIMD, qkvb);

    // 4) attention: split-K partials + combine
    attn_mfma<<<dim3(80, HH, BB), 256, 0, stream>>>(qkvb, part);
    attn_combine<<<NTOK * HH * 16 / 256, 256, 0, stream>>>(part, attw);

    // 5) x_mid = x + gate1 * (attw @ Wout^T + bout)  (bf16 out -> xmid)
    gemm_bf16<3, 64><<<dim3(DIMD / 64, NTOK / 128), 256, 0, stream>>>(
        attw, wo, bout, x, modw, NTOK, DIMD, DIMD, xmid);

    // 6) h2 = LN(x_mid)*(1+scale2)+shift2  (bf16 out; x_mid bf16)
    adaln_ln<1><<<NTOK, 256, 0, stream>>>(xmid, modw, h12, 1536, 2048);

    // 7) hid = gelu(h2 @ W1^T + b1)  (bf16 out)
    gemm_bf16<2, 128><<<dim3(MLPD / 128, NTOK / 128), 256, 0, stream>>>(
        h12, w1, b1, nullptr, nullptr, NTOK, MLPD, DIMD, hid);

    // 8) d_out = x_mid + gate2 * (hid @ W2^T + b2)  (fp32 out; xmid bf16 read)
    gemm_bf16<4, 64><<<dim3(DIMD / 64, NTOK / 128), 256, 0, stream>>>(
        hid, w2, b2, (const float*)xmid, modw, NTOK, DIMD, MLPD, out);
}